// Round 1
// 6200.290 us; speedup vs baseline: 2.3617x; 2.3617x over previous
//
#include <hip/hip_runtime.h>
#include <hip/hip_bf16.h>
#include <math.h>

#define D 512
#define H 8
#define FF 2048
#define V 10000
#define NLAYERS 6
#define BB 8
#define S 512
#define DK 64
#define BS (BB*S)   /* 4096 rows */

// dtypes follow the REFERENCE: float32 in/out.
typedef float WT;
typedef float OT;

__device__ __forceinline__ float tof(float x){ return x; }

// ---------------------------------------------------------------------------
// Embedding + sinusoidal positional encoding
// ---------------------------------------------------------------------------
__global__ __launch_bounds__(256) void embed_kernel(const int* __restrict__ tok,
                                                    const WT* __restrict__ emb,
                                                    float* __restrict__ x)
{
    int r = blockIdx.x;            // [0, BS)
    int s = r % S;
    int tk = tok[r];
    int t = threadIdx.x;
    const float c = -logf(10000.f) / (float)D;
#pragma unroll
    for (int p = 0; p < 2; ++p) {
        int d = t + p * 256;
        int i2 = d & ~1;
        float ang = (float)s * expf((float)i2 * c);
        float pe = (d & 1) ? cosf(ang) : sinf(ang);
        x[(long)r * D + d] = tof(emb[(long)tk * D + d]) + pe;
    }
}

// ---------------------------------------------------------------------------
// Masked softmax over rows of scores [B*H, S, S].
// ---------------------------------------------------------------------------
__global__ __launch_bounds__(256) void softmax_kernel(float* __restrict__ sc,
                                                      const int* __restrict__ tok,
                                                      int causal)
{
    __shared__ float red[4];
    long r = blockIdx.x;                 // [0, B*H*S)
    int i = (int)(r % S);
    int b = (int)(r / ((long)H * S));
    float* row = sc + r * (long)S;
    int t = threadIdx.x;
    float v0 = row[t], v1 = row[t + 256];
    if (causal) {
        if (t > i)        v0 = -INFINITY;
        if (t + 256 > i)  v1 = -INFINITY;
    } else {
        if (tok[b * S + t] == 0)        v0 = -INFINITY;
        if (tok[b * S + t + 256] == 0)  v1 = -INFINITY;
    }
    float m = fmaxf(v0, v1);
    for (int off = 32; off; off >>= 1) m = fmaxf(m, __shfl_down(m, off));
    if ((t & 63) == 0) red[t >> 6] = m;
    __syncthreads();
    m = fmaxf(fmaxf(red[0], red[1]), fmaxf(red[2], red[3]));
    __syncthreads();
    float e0 = expf(v0 - m), e1 = expf(v1 - m);
    float ssum = e0 + e1;
    for (int off = 32; off; off >>= 1) ssum += __shfl_down(ssum, off);
    if ((t & 63) == 0) red[t >> 6] = ssum;
    __syncthreads();
    ssum = red[0] + red[1] + red[2] + red[3];
    float inv = 1.0f / ssum;
    row[t]       = e0 * inv;
    row[t + 256] = e1 * inv;
}

// ---------------------------------------------------------------------------
// In-place residual + LayerNorm
// ---------------------------------------------------------------------------
__global__ __launch_bounds__(256) void ln_kernel(float* __restrict__ x,
                                                 const float* __restrict__ a,
                                                 const WT* __restrict__ g,
                                                 const WT* __restrict__ bb)
{
    __shared__ float red[4];
    long r = blockIdx.x;
    float* xr = x + r * D;
    const float* ar = a + r * D;
    int t = threadIdx.x;
    float v0 = xr[t] + ar[t];
    float v1 = xr[t + 256] + ar[t + 256];
    float s = v0 + v1;
    for (int off = 32; off; off >>= 1) s += __shfl_down(s, off);
    if ((t & 63) == 0) red[t >> 6] = s;
    __syncthreads();
    float mu = (red[0] + red[1] + red[2] + red[3]) * (1.0f / D);
    __syncthreads();
    float d0 = v0 - mu, d1 = v1 - mu;
    float q = d0 * d0 + d1 * d1;
    for (int off = 32; off; off >>= 1) q += __shfl_down(q, off);
    if ((t & 63) == 0) red[t >> 6] = q;
    __syncthreads();
    float var = (red[0] + red[1] + red[2] + red[3]) * (1.0f / D);
    float inv = rsqrtf(var + 1e-5f);
    xr[t]       = d0 * inv * tof(g[t])       + tof(bb[t]);
    xr[t + 256] = d1 * inv * tof(g[t + 256]) + tof(bb[t + 256]);
}

// ---------------------------------------------------------------------------
// Split-bf16 MFMA GEMM (fp32-accurate via hi/lo decomposition, 3 MFMAs/pair).
//
//   C[z][m,n] = alpha * sum_k A[z][m,k] * B'[z][k,n] (+ bias[n]) (opt. ReLU)
//   B' = B (TRANSB=0, B is [K,N] ld=ldb) or B^T (TRANSB=1, B is [N,K] ld=ldb)
//   z -> zb = z/Hdiv, zh = z%Hdiv; per-operand offsets zb*s?b + zh*s?h.
//
//   Tile BM x BN, BK=32, 256 threads = 4 waves (2x2), per-wave (BM/2)x(BN/2),
//   MFMA 16x16x32 bf16. Each f32 x = hi(bf16,trunc) + lo(bf16,rne residual);
//   acc += hiA*hiB + hiA*loB + loA*hiB  (lo*lo ~2^-18, dropped).
//
//   LDS rows (one per m / per n): 128 B = 4 groups of [hi 8k:16B][lo 8k:16B];
//   16B slot s stored at s ^ (row&7)  -> conflict-free b128 reads AND writes.
//
//   Requirements (hold for all call sites): K%32==0, M%BM==0; N guarded.
// ---------------------------------------------------------------------------
typedef __attribute__((ext_vector_type(8))) short bf16x8;
typedef __attribute__((ext_vector_type(4))) float f32x4;

__device__ __forceinline__ void splitf(float x, short& h, short& l)
{
    unsigned u = __float_as_uint(x);
    h = (short)(u >> 16);                                   // truncated hi
    float hf = __uint_as_float(u & 0xffff0000u);
    unsigned v = __float_as_uint(x - hf);                   // exact residual
    l = (short)((v + 0x7fffu + ((v >> 16) & 1u)) >> 16);    // RNE lo
}

template<int BM, int BN, bool TRANSB, bool RELU>
__global__ __launch_bounds__(256, 2) void mm_kernel(
    const float* __restrict__ A, int lda, long sAb, long sAh,
    const float* __restrict__ Bm, int ldb, long sBb, long sBh,
    const float* __restrict__ bias, long sbias,
    float* __restrict__ C, int ldc, long sCb, long sCh,
    int M, int N, int K, int Hdiv, float alpha)
{
    constexpr int MREP = BM / 32;
    constexpr int NREP = BN / 32;
    __shared__ __align__(16) char ldsA[BM * 128];
    __shared__ __align__(16) char ldsB[BN * 128];

    int z = blockIdx.z;
    int zb = z / Hdiv, zh = z % Hdiv;
    A  += (long)zb * sAb + (long)zh * sAh;
    Bm += (long)zb * sBb + (long)zh * sBh;
    C  += (long)zb * sCb + (long)zh * sCh;
    const float* bp = bias ? (bias + (long)zh * sbias) : nullptr;

    int m0 = blockIdx.y * BM;
    int n0 = blockIdx.x * BN;
    int t  = threadIdx.x;
    int g  = t & 3;          // staging: which 8-wide k-octet of the 32-slab
    int rr = t >> 2;         // staging: row 0..63 (per 64-row pass)
    int l  = t & 63;
    int w  = t >> 6;
    int wm = w >> 1, wn = w & 1;
    int lr = l & 15, kg = l >> 4;

    // Fragment-read byte offsets (constant over the K loop).
    int aoh[MREP], aol[MREP], boh[NREP], bol[NREP];
#pragma unroll
    for (int mi = 0; mi < MREP; ++mi) {
        int r = wm * (BM / 2) + mi * 16 + lr;
        aoh[mi] = r * 128 + (((2 * kg)     ^ (r & 7)) << 4);
        aol[mi] = r * 128 + (((2 * kg + 1) ^ (r & 7)) << 4);
    }
#pragma unroll
    for (int ni = 0; ni < NREP; ++ni) {
        int r = wn * (BN / 2) + ni * 16 + lr;
        boh[ni] = r * 128 + (((2 * kg)     ^ (r & 7)) << 4);
        bol[ni] = r * 128 + (((2 * kg + 1) ^ (r & 7)) << 4);
    }

    f32x4 acc[MREP][NREP];
#pragma unroll
    for (int mi = 0; mi < MREP; ++mi)
#pragma unroll
        for (int ni = 0; ni < NREP; ++ni)
            acc[mi][ni] = (f32x4){0.f, 0.f, 0.f, 0.f};

    for (int k0 = 0; k0 < K; k0 += 32) {
        if (k0) __syncthreads();
        // ---- stage A tile: [m][k] rows, hi/lo split ----
#pragma unroll
        for (int i = 0; i < BM / 64; ++i) {
            int r = rr + 64 * i;
            const float4* p = (const float4*)(A + (long)(m0 + r) * lda + (k0 + 8 * g));
            float4 f0 = p[0], f1 = p[1];
            float f[8] = {f0.x, f0.y, f0.z, f0.w, f1.x, f1.y, f1.z, f1.w};
            bf16x8 hv, lv;
#pragma unroll
            for (int j = 0; j < 8; ++j) { short hh, ll; splitf(f[j], hh, ll); hv[j] = hh; lv[j] = ll; }
            char* rd = ldsA + r * 128;
            *(bf16x8*)(rd + (((2 * g)     ^ (r & 7)) << 4)) = hv;
            *(bf16x8*)(rd + (((2 * g + 1) ^ (r & 7)) << 4)) = lv;
        }
        // ---- stage B tile: lds rows are n, k-contiguous ----
#pragma unroll
        for (int i = 0; i < BN / 64; ++i) {
            int r = rr + 64 * i;
            float f[8];
            if (TRANSB) {          // B is [N,K]: same pattern as A
                const float4* p = (const float4*)(Bm + (long)(n0 + r) * ldb + (k0 + 8 * g));
                float4 f0 = p[0], f1 = p[1];
                f[0]=f0.x; f[1]=f0.y; f[2]=f0.z; f[3]=f0.w;
                f[4]=f1.x; f[5]=f1.y; f[6]=f1.z; f[7]=f1.w;
            } else {               // B is [K,N]: gather-transpose (coalesced across lanes)
                int gn = n0 + r;
                bool ok = gn < N;
                const float* p = Bm + (long)(k0 + 8 * g) * ldb + gn;
#pragma unroll
                for (int j = 0; j < 8; ++j) f[j] = ok ? p[(long)j * ldb] : 0.f;
            }
            bf16x8 hv, lv;
#pragma unroll
            for (int j = 0; j < 8; ++j) { short hh, ll; splitf(f[j], hh, ll); hv[j] = hh; lv[j] = ll; }
            char* rd = ldsB + r * 128;
            *(bf16x8*)(rd + (((2 * g)     ^ (r & 7)) << 4)) = hv;
            *(bf16x8*)(rd + (((2 * g + 1) ^ (r & 7)) << 4)) = lv;
        }
        __syncthreads();
        // ---- fragments + MFMA ----
        bf16x8 ah[MREP], al_[MREP], bh[NREP], bl_[NREP];
#pragma unroll
        for (int mi = 0; mi < MREP; ++mi) {
            ah[mi]  = *(const bf16x8*)(ldsA + aoh[mi]);
            al_[mi] = *(const bf16x8*)(ldsA + aol[mi]);
        }
#pragma unroll
        for (int ni = 0; ni < NREP; ++ni) {
            bh[ni]  = *(const bf16x8*)(ldsB + boh[ni]);
            bl_[ni] = *(const bf16x8*)(ldsB + bol[ni]);
        }
#pragma unroll
        for (int mi = 0; mi < MREP; ++mi)
#pragma unroll
            for (int ni = 0; ni < NREP; ++ni) {
                acc[mi][ni] = __builtin_amdgcn_mfma_f32_16x16x32_bf16(ah[mi],  bh[ni],  acc[mi][ni], 0, 0, 0);
                acc[mi][ni] = __builtin_amdgcn_mfma_f32_16x16x32_bf16(ah[mi],  bl_[ni], acc[mi][ni], 0, 0, 0);
                acc[mi][ni] = __builtin_amdgcn_mfma_f32_16x16x32_bf16(al_[mi], bh[ni],  acc[mi][ni], 0, 0, 0);
            }
    }
    // ---- epilogue: C[row = 4*kg + j (+16*mi + wave/blk), col = lr (+...)] ----
#pragma unroll
    for (int mi = 0; mi < MREP; ++mi) {
        int mrow = m0 + wm * (BM / 2) + mi * 16 + kg * 4;
#pragma unroll
        for (int ni = 0; ni < NREP; ++ni) {
            int col = n0 + wn * (BN / 2) + ni * 16 + lr;
            if (col < N) {
                float bv = bp ? bp[col] : 0.f;
#pragma unroll
                for (int j = 0; j < 4; ++j) {
                    float v2 = acc[mi][ni][j] * alpha + bv;
                    if (RELU) v2 = fmaxf(v2, 0.f);
                    C[(long)(mrow + j) * ldc + col] = v2;
                }
            }
        }
    }
}

// ---------------------------------------------------------------------------
extern "C" void kernel_launch(void* const* d_in, const int* in_sizes, int n_in,
                              void* d_out, int out_size, void* d_ws, size_t ws_size,
                              hipStream_t stream)
{
    const int* src      = (const int*)d_in[0];
    const int* tgt      = (const int*)d_in[1];
    const WT*  src_emb  = (const WT*)d_in[2];
    const WT*  tgt_emb  = (const WT*)d_in[3];
    const WT* enc_qkvo_w = (const WT*)d_in[4];
    const WT* enc_qkvo_b = (const WT*)d_in[5];
    const WT* enc_ff1_w  = (const WT*)d_in[6];
    const WT* enc_ff1_b  = (const WT*)d_in[7];
    const WT* enc_ff2_w  = (const WT*)d_in[8];
    const WT* enc_ff2_b  = (const WT*)d_in[9];
    const WT* enc_ln_g   = (const WT*)d_in[10];
    const WT* enc_ln_b   = (const WT*)d_in[11];
    const WT* dec_sa_w   = (const WT*)d_in[12];
    const WT* dec_sa_b   = (const WT*)d_in[13];
    const WT* dec_ca_w   = (const WT*)d_in[14];
    const WT* dec_ca_b   = (const WT*)d_in[15];
    const WT* dec_ff1_w  = (const WT*)d_in[16];
    const WT* dec_ff1_b  = (const WT*)d_in[17];
    const WT* dec_ff2_w  = (const WT*)d_in[18];
    const WT* dec_ff2_b  = (const WT*)d_in[19];
    const WT* dec_ln_g   = (const WT*)d_in[20];
    const WT* dec_ln_b   = (const WT*)d_in[21];
    const WT* out_w      = (const WT*)d_in[22];
    const WT* out_b      = (const WT*)d_in[23];
    OT* out = (OT*)d_out;

    // Workspace layout (f32), same aliasing as before:
    //   bx, by, bmha persistent; bq/bk/bv contiguous (enables fused QKV batch);
    //   batt aliases bq; bsc (scores) | bffn (FF hidden) alias.
    float* bx   = (float*)d_ws;
    float* by   = bx   + (size_t)BS * D;
    float* bmha = by   + (size_t)BS * D;
    float* bq   = bmha + (size_t)BS * D;
    float* bk   = bq   + (size_t)BS * D;
    float* bv   = bk   + (size_t)BS * D;
    float* batt = bq;                        // alias
    float* bsc  = bv   + (size_t)BS * D;     // [B*H, S, S]
    float* bffn = bsc;                       // alias, [BS, FF]

    dim3 blk(256);

    auto attn = [&](const float* xq, const float* xkv, const WT* w, const WT* b,
                    const int* masktok, int causal, float* outbuf) {
        if (xq == xkv) {
            // Fused Q,K,V projection: z in {0,1,2} selects weight/bias/output.
            dim3 g(D / 128, BS / 128, 3);
            mm_kernel<128, 128, false, false><<<g, blk, 0, stream>>>(
                xq, D, 0, 0, w, D, 0, (long)D * D, b, D,
                bq, D, 0, (long)BS * D, BS, D, D, 3, 1.0f);
        } else {
            dim3 gq(D / 64, BS / 128, 1);
            mm_kernel<128, 64, false, false><<<gq, blk, 0, stream>>>(
                xq, D, 0, 0, w, D, 0, 0, b, 0,
                bq, D, 0, 0, BS, D, D, 1, 1.0f);
            dim3 gkv(D / 128, BS / 128, 2);
            mm_kernel<128, 128, false, false><<<gkv, blk, 0, stream>>>(
                xkv, D, 0, 0, w + (size_t)D * D, D, 0, (long)D * D, b + D, D,
                bk, D, 0, (long)BS * D, BS, D, D, 2, 1.0f);
        }
        {   // scores[z] = 0.125 * Q K^T   (z = b*H + h)
            dim3 g(S / 128, S / 128, BB * H);
            mm_kernel<128, 128, true, false><<<g, blk, 0, stream>>>(
                bq, D, (long)S * D, DK, bk, D, (long)S * D, DK, nullptr, 0,
                bsc, S, (long)H * S * S, (long)S * S, S, S, DK, H, 0.125f);
        }
        softmax_kernel<<<dim3(BB * H * S), blk, 0, stream>>>(bsc, masktok, causal);
        {   // context[z] = P V   (batt aliases bq — Q is dead here)
            dim3 g(1, S / 64, BB * H);
            mm_kernel<64, 64, false, false><<<g, blk, 0, stream>>>(
                bsc, S, (long)H * S * S, (long)S * S, bv, D, (long)S * D, DK, nullptr, 0,
                batt, D, (long)S * D, DK, S, DK, S, H, 1.0f);
        }
        {   // output projection
            dim3 g(D / 64, BS / 128, 1);
            mm_kernel<128, 64, false, false><<<g, blk, 0, stream>>>(
                batt, D, 0, 0, w + 3 * (size_t)D * D, D, 0, 0, b + 3 * D, 0,
                outbuf, D, 0, 0, BS, D, D, 1, 1.0f);
        }
    };

    auto ffn = [&](float* x, const WT* w1, const WT* b1, const WT* w2, const WT* b2) {
        dim3 g1(FF / 128, BS / 128, 1);
        mm_kernel<128, 128, false, true><<<g1, blk, 0, stream>>>(
            x, D, 0, 0, w1, FF, 0, 0, b1, 0,
            bffn, FF, 0, 0, BS, FF, D, 1, 1.0f);
        dim3 g2(D / 64, BS / 128, 1);
        mm_kernel<128, 64, false, false><<<g2, blk, 0, stream>>>(
            bffn, FF, 0, 0, w2, D, 0, 0, b2, 0,
            bmha, D, 0, 0, BS, D, FF, 1, 1.0f);
    };

    // ---------------- encoder ----------------
    embed_kernel<<<dim3(BS), blk, 0, stream>>>(src, src_emb, bx);
    for (int l = 0; l < NLAYERS; ++l) {
        const WT* w = enc_qkvo_w + (size_t)l * 4 * D * D;
        const WT* b = enc_qkvo_b + (size_t)l * 4 * D;
        attn(bx, bx, w, b, src, 0, bmha);
        ln_kernel<<<dim3(BS), blk, 0, stream>>>(bx, bmha,
            enc_ln_g + (size_t)l * 2 * D, enc_ln_b + (size_t)l * 2 * D);
        ffn(bx, enc_ff1_w + (size_t)l * D * FF, enc_ff1_b + (size_t)l * FF,
            enc_ff2_w + (size_t)l * FF * D, enc_ff2_b + (size_t)l * D);
        ln_kernel<<<dim3(BS), blk, 0, stream>>>(bx, bmha,
            enc_ln_g + (size_t)l * 2 * D + D, enc_ln_b + (size_t)l * 2 * D + D);
    }

    // ---------------- decoder ----------------
    embed_kernel<<<dim3(BS), blk, 0, stream>>>(tgt, tgt_emb, by);
    for (int l = 0; l < NLAYERS; ++l) {
        attn(by, by, dec_sa_w + (size_t)l * 4 * D * D, dec_sa_b + (size_t)l * 4 * D,
             nullptr, 1, bmha);
        ln_kernel<<<dim3(BS), blk, 0, stream>>>(by, bmha,
            dec_ln_g + (size_t)l * 3 * D, dec_ln_b + (size_t)l * 3 * D);
        // cross-attention; reference masks keys with TGT padding (bug-for-bug)
        attn(by, bx, dec_ca_w + (size_t)l * 4 * D * D, dec_ca_b + (size_t)l * 4 * D,
             tgt, 0, bmha);
        ln_kernel<<<dim3(BS), blk, 0, stream>>>(by, bmha,
            dec_ln_g + (size_t)l * 3 * D + D, dec_ln_b + (size_t)l * 3 * D + D);
        ffn(by, dec_ff1_w + (size_t)l * D * FF, dec_ff1_b + (size_t)l * FF,
            dec_ff2_w + (size_t)l * FF * D, dec_ff2_b + (size_t)l * D);
        ln_kernel<<<dim3(BS), blk, 0, stream>>>(by, bmha,
            dec_ln_g + (size_t)l * 3 * D + 2 * D, dec_ln_b + (size_t)l * 3 * D + 2 * D);
    }

    // ---------------- final projection to vocab ----------------
    {
        dim3 g((V + 127) / 128, BS / 128, 1);
        mm_kernel<128, 128, false, false><<<g, blk, 0, stream>>>(
            by, D, 0, 0, out_w, V, 0, 0, out_b, 0,
            out, V, 0, 0, BS, V, D, 1, 1.0f);
    }
}

// Round 2
// 5888.863 us; speedup vs baseline: 2.4866x; 1.0529x over previous
//
#include <hip/hip_runtime.h>
#include <math.h>

#define D 512
#define H 8
#define FF 2048
#define V 10000
#define NLAYERS 6
#define BB 8
#define S 512
#define DK 64
#define BS (BB*S)   /* 4096 rows */

typedef float WT;
typedef float OT;

// ---------------------------------------------------------------------------
// split32 format: one u32 per element = (bf16_hi << 16) | bf16_lo, where
// hi = truncate-to-bf16(x), lo = RNE-bf16(x - hi).  x ~= hi + lo to ~2^-17 rel.
// ---------------------------------------------------------------------------
__device__ __forceinline__ unsigned packsplit(float v)
{
    unsigned u = __float_as_uint(v);
    unsigned h = u & 0xffff0000u;
    float r = v - __uint_as_float(h);
    unsigned w = __float_as_uint(r);
    unsigned l = (w + 0x7fffu + ((w >> 16) & 1u)) >> 16;
    return h | (l & 0xffffu);
}

__device__ __forceinline__ void splitf(float x, unsigned short& h, unsigned short& l)
{
    unsigned u = __float_as_uint(x);
    h = (unsigned short)(u >> 16);
    float hf = __uint_as_float(u & 0xffff0000u);
    unsigned v = __float_as_uint(x - hf);
    l = (unsigned short)((v + 0x7fffu + ((v >> 16) & 1u)) >> 16);
}

// ---------------------------------------------------------------------------
// Embedding + positional encoding: writes f32 (residual) + split32 planes.
// ---------------------------------------------------------------------------
__global__ __launch_bounds__(256) void embed_kernel(const int* __restrict__ tok,
                                                    const WT* __restrict__ emb,
                                                    float* __restrict__ x,
                                                    unsigned* __restrict__ xs)
{
    int r = blockIdx.x;
    int s = r % S;
    int tk = tok[r];
    int t = threadIdx.x;
    const float c = -logf(10000.f) / (float)D;
#pragma unroll
    for (int p = 0; p < 2; ++p) {
        int d = t + p * 256;
        int i2 = d & ~1;
        float ang = (float)s * expf((float)i2 * c);
        float pe = (d & 1) ? cosf(ang) : sinf(ang);
        float v = emb[(long)tk * D + d] + pe;
        x[(long)r * D + d] = v;
        xs[(long)r * D + d] = packsplit(v);
    }
}

// ---------------------------------------------------------------------------
// Masked softmax over rows of the current z-half of scores.
// rbase = global row offset of this half (for batch index of padding mask).
// ---------------------------------------------------------------------------
__global__ __launch_bounds__(256) void softmax_kernel(float* __restrict__ sc,
                                                      const int* __restrict__ tok,
                                                      int causal, int rbase)
{
    __shared__ float red[4];
    long r = blockIdx.x;                 // local row in this half
    int i = (int)(r % S);
    int b = (int)(((long)rbase + r) / ((long)H * S));
    float* row = sc + r * (long)S;
    int t = threadIdx.x;
    float v0 = row[t], v1 = row[t + 256];
    if (causal) {
        if (t > i)        v0 = -INFINITY;
        if (t + 256 > i)  v1 = -INFINITY;
    } else {
        if (tok[b * S + t] == 0)        v0 = -INFINITY;
        if (tok[b * S + t + 256] == 0)  v1 = -INFINITY;
    }
    float m = fmaxf(v0, v1);
    for (int off = 32; off; off >>= 1) m = fmaxf(m, __shfl_down(m, off));
    if ((t & 63) == 0) red[t >> 6] = m;
    __syncthreads();
    m = fmaxf(fmaxf(red[0], red[1]), fmaxf(red[2], red[3]));
    __syncthreads();
    float e0 = expf(v0 - m), e1 = expf(v1 - m);
    float ssum = e0 + e1;
    for (int off = 32; off; off >>= 1) ssum += __shfl_down(ssum, off);
    if ((t & 63) == 0) red[t >> 6] = ssum;
    __syncthreads();
    ssum = red[0] + red[1] + red[2] + red[3];
    float inv = 1.0f / ssum;
    row[t]       = e0 * inv;
    row[t + 256] = e1 * inv;
}

// ---------------------------------------------------------------------------
// In-place residual + LayerNorm; also emits split32 of the output.
// ---------------------------------------------------------------------------
__global__ __launch_bounds__(256) void ln_kernel(float* __restrict__ x,
                                                 const float* __restrict__ a,
                                                 const WT* __restrict__ g,
                                                 const WT* __restrict__ bb,
                                                 unsigned* __restrict__ xs)
{
    __shared__ float red[4];
    long r = blockIdx.x;
    float* xr = x + r * D;
    const float* ar = a + r * D;
    int t = threadIdx.x;
    float v0 = xr[t] + ar[t];
    float v1 = xr[t + 256] + ar[t + 256];
    float s = v0 + v1;
    for (int off = 32; off; off >>= 1) s += __shfl_down(s, off);
    if ((t & 63) == 0) red[t >> 6] = s;
    __syncthreads();
    float mu = (red[0] + red[1] + red[2] + red[3]) * (1.0f / D);
    __syncthreads();
    float d0 = v0 - mu, d1 = v1 - mu;
    float q = d0 * d0 + d1 * d1;
    for (int off = 32; off; off >>= 1) q += __shfl_down(q, off);
    if ((t & 63) == 0) red[t >> 6] = q;
    __syncthreads();
    float var = (red[0] + red[1] + red[2] + red[3]) * (1.0f / D);
    float inv = rsqrtf(var + 1e-5f);
    float o0 = d0 * inv * g[t]       + bb[t];
    float o1 = d1 * inv * g[t + 256] + bb[t + 256];
    xr[t]       = o0;
    xr[t + 256] = o1;
    xs[r * D + t]       = packsplit(o0);
    xs[r * D + t + 256] = packsplit(o1);
}

// ---------------------------------------------------------------------------
// Weight split+transpose: W f32 [Z][K][N] -> O split32 [Z][N][K].
// Coalesced read along n, LDS-transposed, 16B coalesced writes along k.
// ---------------------------------------------------------------------------
__global__ __launch_bounds__(256) void wsplit_kernel(const float* __restrict__ W,
                                                     unsigned* __restrict__ O,
                                                     int K, int N)
{
    __shared__ unsigned tb[64][65];
    long zoff = (long)blockIdx.z * K * N;
    W += zoff; O += zoff;
    int n0 = blockIdx.x * 64, k0 = blockIdx.y * 64;
    int t = threadIdx.x;
#pragma unroll
    for (int i = 0; i < 16; ++i) {
        int idx = t + 256 * i;
        int kk = idx >> 6, nn = idx & 63;
        int gn = n0 + nn;
        float v = (gn < N) ? W[(long)(k0 + kk) * N + gn] : 0.f;
        tb[nn][kk] = packsplit(v);
    }
    __syncthreads();
#pragma unroll
    for (int i = 0; i < 4; ++i) {
        int idx = t + 256 * i;
        int nn = idx >> 4, kk = (idx & 15) * 4;
        int gn = n0 + nn;
        if (gn < N) {
            uint4 o;
            o.x = tb[nn][kk]; o.y = tb[nn][kk + 1];
            o.z = tb[nn][kk + 2]; o.w = tb[nn][kk + 3];
            *(uint4*)&O[(long)gn * K + k0 + kk] = o;
        }
    }
}

// ---------------------------------------------------------------------------
// Split-bf16 MFMA GEMM.  C = alpha * A @ B^T(+layout) + bias, optional ReLU.
// A modes: A_SPLIT (split32 [M][K], lda)     | A_F32 (f32, split on the fly)
// B modes: B_SPLIT (split32 [N][K], ldb=row) | B_GATH (split32 [K][N], ldb)
// C modes: CSPLIT  (split32 out)             | f32 out
// Tile BM x BN, BK=32, 256 thr = 4 waves (2x2), MFMA 16x16x32 bf16, 3/pair.
// LDS row per m (or n): 128B = slots; slot s of row r stored at s^(r&7).
// ---------------------------------------------------------------------------
#define A_SPLIT 0
#define A_F32   1
#define B_SPLIT 0
#define B_GATH  1

typedef __attribute__((ext_vector_type(8))) short bf16x8;
typedef __attribute__((ext_vector_type(4))) float f32x4;

template<int BM, int BN, int AMODE, int BMODE, bool RELU, bool CSPLIT>
__global__ __launch_bounds__(256, 2) void mm_kernel(
    const void* __restrict__ Av, int lda, long sAb, long sAh,
    const void* __restrict__ Bv, int ldb, long sBb, long sBh,
    const float* __restrict__ bias, long sbias,
    void* __restrict__ Cv, int ldc, long sCb, long sCh,
    int M, int N, int K, int Hdiv, float alpha)
{
    constexpr int MREP = BM / 32;
    constexpr int NREP = BN / 32;
    __shared__ __align__(16) char ldsA[BM * 128];
    __shared__ __align__(16) char ldsB[BN * 128];

    int z = blockIdx.z;
    int zb = z / Hdiv, zh = z - zb * Hdiv;
    long aoff = (long)zb * sAb + (long)zh * sAh;
    long boff = (long)zb * sBb + (long)zh * sBh;
    long coff = (long)zb * sCb + (long)zh * sCh;
    const float* bp = bias ? (bias + (long)zh * sbias) : nullptr;

    int m0 = blockIdx.y * BM;
    int n0 = blockIdx.x * BN;
    int t  = threadIdx.x;
    int g  = t & 3;          // staging: k-octet of the 32-slab
    int rr = t >> 2;         // staging: row 0..63 per pass
    int l  = t & 63;
    int w  = t >> 6;
    int wm = w >> 1, wn = w & 1;
    int lr = l & 15, kg = l >> 4;

    int aoh[MREP], aol[MREP], boh[NREP], bol[NREP];
#pragma unroll
    for (int mi = 0; mi < MREP; ++mi) {
        int r = wm * (BM / 2) + mi * 16 + lr;
        aoh[mi] = r * 128 + (((2 * kg)     ^ (r & 7)) << 4);
        aol[mi] = r * 128 + (((2 * kg + 1) ^ (r & 7)) << 4);
    }
#pragma unroll
    for (int ni = 0; ni < NREP; ++ni) {
        int r = wn * (BN / 2) + ni * 16 + lr;
        boh[ni] = r * 128 + (((2 * kg)     ^ (r & 7)) << 4);
        bol[ni] = r * 128 + (((2 * kg + 1) ^ (r & 7)) << 4);
    }

    f32x4 acc[MREP][NREP];
#pragma unroll
    for (int mi = 0; mi < MREP; ++mi)
#pragma unroll
        for (int ni = 0; ni < NREP; ++ni)
            acc[mi][ni] = (f32x4){0.f, 0.f, 0.f, 0.f};

    for (int k0 = 0; k0 < K; k0 += 32) {
        if (k0) __syncthreads();
        // ---- stage A ----
        if (AMODE == A_SPLIT) {
            const unsigned* A = (const unsigned*)Av + aoff;
#pragma unroll
            for (int i = 0; i < BM / 64; ++i) {
                int r = rr + 64 * i;
                const uint4* p = (const uint4*)(A + (long)(m0 + r) * lda + (k0 + 8 * g));
                uint4 q0 = p[0], q1 = p[1];
                uint4 hv, lv;
                hv.x = (q0.x >> 16) | (q0.y & 0xffff0000u);
                hv.y = (q0.z >> 16) | (q0.w & 0xffff0000u);
                hv.z = (q1.x >> 16) | (q1.y & 0xffff0000u);
                hv.w = (q1.z >> 16) | (q1.w & 0xffff0000u);
                lv.x = (q0.x & 0xffffu) | (q0.y << 16);
                lv.y = (q0.z & 0xffffu) | (q0.w << 16);
                lv.z = (q1.x & 0xffffu) | (q1.y << 16);
                lv.w = (q1.z & 0xffffu) | (q1.w << 16);
                char* rd = ldsA + r * 128;
                *(uint4*)(rd + (((2 * g)     ^ (r & 7)) << 4)) = hv;
                *(uint4*)(rd + (((2 * g + 1) ^ (r & 7)) << 4)) = lv;
            }
        } else {  // A_F32: split on the fly
            const float* A = (const float*)Av + aoff;
#pragma unroll
            for (int i = 0; i < BM / 64; ++i) {
                int r = rr + 64 * i;
                const float4* p = (const float4*)(A + (long)(m0 + r) * lda + (k0 + 8 * g));
                float4 f0 = p[0], f1 = p[1];
                float f[8] = {f0.x, f0.y, f0.z, f0.w, f1.x, f1.y, f1.z, f1.w};
                uint4 hv, lv;
                unsigned hw[4], lw[4];
#pragma unroll
                for (int jj = 0; jj < 4; ++jj) {
                    unsigned short h0, l0, h1, l1;
                    splitf(f[2 * jj], h0, l0);
                    splitf(f[2 * jj + 1], h1, l1);
                    hw[jj] = (unsigned)h0 | ((unsigned)h1 << 16);
                    lw[jj] = (unsigned)l0 | ((unsigned)l1 << 16);
                }
                hv.x = hw[0]; hv.y = hw[1]; hv.z = hw[2]; hv.w = hw[3];
                lv.x = lw[0]; lv.y = lw[1]; lv.z = lw[2]; lv.w = lw[3];
                char* rd = ldsA + r * 128;
                *(uint4*)(rd + (((2 * g)     ^ (r & 7)) << 4)) = hv;
                *(uint4*)(rd + (((2 * g + 1) ^ (r & 7)) << 4)) = lv;
            }
        }
        // ---- stage B ----
        if (BMODE == B_SPLIT) {
            const unsigned* B = (const unsigned*)Bv + boff;
#pragma unroll
            for (int i = 0; i < BN / 64; ++i) {
                int r = rr + 64 * i;
                int gn = n0 + r;
                uint4 hv, lv;
                if (gn < N) {
                    const uint4* p = (const uint4*)(B + (long)gn * ldb + (k0 + 8 * g));
                    uint4 q0 = p[0], q1 = p[1];
                    hv.x = (q0.x >> 16) | (q0.y & 0xffff0000u);
                    hv.y = (q0.z >> 16) | (q0.w & 0xffff0000u);
                    hv.z = (q1.x >> 16) | (q1.y & 0xffff0000u);
                    hv.w = (q1.z >> 16) | (q1.w & 0xffff0000u);
                    lv.x = (q0.x & 0xffffu) | (q0.y << 16);
                    lv.y = (q0.z & 0xffffu) | (q0.w << 16);
                    lv.z = (q1.x & 0xffffu) | (q1.y << 16);
                    lv.w = (q1.z & 0xffffu) | (q1.w << 16);
                } else {
                    hv.x = hv.y = hv.z = hv.w = 0u;
                    lv.x = lv.y = lv.z = lv.w = 0u;
                }
                char* rd = ldsB + r * 128;
                *(uint4*)(rd + (((2 * g)     ^ (r & 7)) << 4)) = hv;
                *(uint4*)(rd + (((2 * g + 1) ^ (r & 7)) << 4)) = lv;
            }
        } else {  // B_GATH: split32 [K][N], gather along k (PV's V)
            const unsigned* B = (const unsigned*)Bv + boff;
#pragma unroll
            for (int i = 0; i < BN / 64; ++i) {
                int r = rr + 64 * i;
                int gn = n0 + r;
                unsigned e[8];
                const unsigned* p = B + (long)(k0 + 8 * g) * ldb + gn;
#pragma unroll
                for (int j = 0; j < 8; ++j) e[j] = (gn < N) ? p[(long)j * ldb] : 0u;
                uint4 hv, lv;
                hv.x = (e[0] >> 16) | (e[1] & 0xffff0000u);
                hv.y = (e[2] >> 16) | (e[3] & 0xffff0000u);
                hv.z = (e[4] >> 16) | (e[5] & 0xffff0000u);
                hv.w = (e[6] >> 16) | (e[7] & 0xffff0000u);
                lv.x = (e[0] & 0xffffu) | (e[1] << 16);
                lv.y = (e[2] & 0xffffu) | (e[3] << 16);
                lv.z = (e[4] & 0xffffu) | (e[5] << 16);
                lv.w = (e[6] & 0xffffu) | (e[7] << 16);
                char* rd = ldsB + r * 128;
                *(uint4*)(rd + (((2 * g)     ^ (r & 7)) << 4)) = hv;
                *(uint4*)(rd + (((2 * g + 1) ^ (r & 7)) << 4)) = lv;
            }
        }
        __syncthreads();
        // ---- fragments + MFMA ----
        bf16x8 ah[MREP], al_[MREP], bh[NREP], bl_[NREP];
#pragma unroll
        for (int mi = 0; mi < MREP; ++mi) {
            ah[mi]  = *(const bf16x8*)(ldsA + aoh[mi]);
            al_[mi] = *(const bf16x8*)(ldsA + aol[mi]);
        }
#pragma unroll
        for (int ni = 0; ni < NREP; ++ni) {
            bh[ni]  = *(const bf16x8*)(ldsB + boh[ni]);
            bl_[ni] = *(const bf16x8*)(ldsB + bol[ni]);
        }
#pragma unroll
        for (int mi = 0; mi < MREP; ++mi)
#pragma unroll
            for (int ni = 0; ni < NREP; ++ni) {
                acc[mi][ni] = __builtin_amdgcn_mfma_f32_16x16x32_bf16(ah[mi],  bh[ni],  acc[mi][ni], 0, 0, 0);
                acc[mi][ni] = __builtin_amdgcn_mfma_f32_16x16x32_bf16(ah[mi],  bl_[ni], acc[mi][ni], 0, 0, 0);
                acc[mi][ni] = __builtin_amdgcn_mfma_f32_16x16x32_bf16(al_[mi], bh[ni],  acc[mi][ni], 0, 0, 0);
            }
    }
    // ---- epilogue ----
#pragma unroll
    for (int mi = 0; mi < MREP; ++mi) {
        int mrow = m0 + wm * (BM / 2) + mi * 16 + kg * 4;
#pragma unroll
        for (int ni = 0; ni < NREP; ++ni) {
            int col = n0 + wn * (BN / 2) + ni * 16 + lr;
            if (col < N) {
                float bvl = bp ? bp[col] : 0.f;
#pragma unroll
                for (int j = 0; j < 4; ++j) {
                    float v2 = acc[mi][ni][j] * alpha + bvl;
                    if (RELU) v2 = fmaxf(v2, 0.f);
                    long ci = coff + (long)(mrow + j) * ldc + col;
                    if (CSPLIT) ((unsigned*)Cv)[ci] = packsplit(v2);
                    else        ((float*)Cv)[ci] = v2;
                }
            }
        }
    }
}

// ---------------------------------------------------------------------------
extern "C" void kernel_launch(void* const* d_in, const int* in_sizes, int n_in,
                              void* d_out, int out_size, void* d_ws, size_t ws_size,
                              hipStream_t stream)
{
    const int* src      = (const int*)d_in[0];
    const int* tgt      = (const int*)d_in[1];
    const WT*  src_emb  = (const WT*)d_in[2];
    const WT*  tgt_emb  = (const WT*)d_in[3];
    const WT* enc_qkvo_w = (const WT*)d_in[4];
    const WT* enc_qkvo_b = (const WT*)d_in[5];
    const WT* enc_ff1_w  = (const WT*)d_in[6];
    const WT* enc_ff1_b  = (const WT*)d_in[7];
    const WT* enc_ff2_w  = (const WT*)d_in[8];
    const WT* enc_ff2_b  = (const WT*)d_in[9];
    const WT* enc_ln_g   = (const WT*)d_in[10];
    const WT* enc_ln_b   = (const WT*)d_in[11];
    const WT* dec_sa_w   = (const WT*)d_in[12];
    const WT* dec_sa_b   = (const WT*)d_in[13];
    const WT* dec_ca_w   = (const WT*)d_in[14];
    const WT* dec_ca_b   = (const WT*)d_in[15];
    const WT* dec_ff1_w  = (const WT*)d_in[16];
    const WT* dec_ff1_b  = (const WT*)d_in[17];
    const WT* dec_ff2_w  = (const WT*)d_in[18];
    const WT* dec_ff2_b  = (const WT*)d_in[19];
    const WT* dec_ln_g   = (const WT*)d_in[20];
    const WT* dec_ln_b   = (const WT*)d_in[21];
    const WT* out_w      = (const WT*)d_in[22];
    const WT* out_b      = (const WT*)d_in[23];
    OT* out = (OT*)d_out;

    // Workspace (100 MB, all 4 B/elem):
    //  bx, by, bmha f32 | bxs, bys, bqs, bks, bvs split32 | wsp 1M u32 (4MB)
    //  | bsc region 32MB: f32 half-z scores OR split32 FF hidden.
    //  vocab weight split (20MB) aliases bqs..bvs (dead at the end).
    const size_t NE = (size_t)BS * D;    // 2M elems
    float*    bx   = (float*)d_ws;
    float*    by   = bx + NE;
    float*    bmha = by + NE;
    unsigned* bxs  = (unsigned*)(bmha + NE);
    unsigned* bys  = bxs + NE;
    unsigned* bqs  = bys + NE;
    unsigned* bks  = bqs + NE;
    unsigned* bvs  = bks + NE;
    unsigned* wsp  = bvs + NE;                         // 4 MB: [4][D][D] or [FF][D] etc.
    float*    bsc  = (float*)(wsp + (size_t)D * FF);   // 32 MB
    unsigned* hidden = (unsigned*)bsc;                 // alias
    unsigned* batts  = bqs;                            // context alias (Q dead)
    unsigned* vws    = bqs;                            // vocab W split alias (20MB)

    dim3 blk(256);

    auto attn = [&](const unsigned* aqs, const unsigned* akvs,
                    const WT* w, const WT* b,
                    const int* masktok, int causal, float* outbuf) {
        // split all 4 weight matrices [4][D][D] -> wsp [4][D][D] packed [N][K]
        wsplit_kernel<<<dim3(8, 8, 4), blk, 0, stream>>>(w, wsp, D, D);
        if (aqs == akvs) {
            mm_kernel<128, 128, A_SPLIT, B_SPLIT, false, true>
                <<<dim3(4, 32, 3), blk, 0, stream>>>(
                aqs, D, 0, 0, wsp, D, 0, (long)D * D, b, D,
                bqs, D, 0, (long)BS * D, BS, D, D, 3, 1.0f);
        } else {
            mm_kernel<128, 64, A_SPLIT, B_SPLIT, false, true>
                <<<dim3(8, 32, 1), blk, 0, stream>>>(
                aqs, D, 0, 0, wsp, D, 0, 0, b, 0,
                bqs, D, 0, 0, BS, D, D, 1, 1.0f);
            mm_kernel<128, 128, A_SPLIT, B_SPLIT, false, true>
                <<<dim3(4, 32, 2), blk, 0, stream>>>(
                akvs, D, 0, 0, wsp + (size_t)D * D, D, 0, (long)D * D, b + D, D,
                bks, D, 0, (long)BS * D, BS, D, D, 2, 1.0f);
        }
        for (int hh = 0; hh < 2; ++hh) {   // z-halves: 32 (b,h) pairs each
            long zo = (long)hh * 4 * S * D;          // elems (zb0 = 4)
            mm_kernel<128, 128, A_SPLIT, B_SPLIT, false, false>
                <<<dim3(4, 4, 32), blk, 0, stream>>>(
                bqs + zo, D, (long)S * D, DK, bks + zo, D, (long)S * D, DK,
                nullptr, 0,
                bsc, S, (long)H * S * S, (long)S * S, S, S, DK, H, 0.125f);
            softmax_kernel<<<dim3(BB * H * S / 2), blk, 0, stream>>>(
                bsc, masktok, causal, hh * (BB * H * S / 2));
            mm_kernel<64, 64, A_F32, B_GATH, false, true>
                <<<dim3(1, 8, 32), blk, 0, stream>>>(
                bsc, S, (long)H * S * S, (long)S * S, bvs + zo, D, (long)S * D, DK,
                nullptr, 0,
                batts + zo, D, (long)S * D, DK, S, DK, S, H, 1.0f);
        }
        mm_kernel<128, 64, A_SPLIT, B_SPLIT, false, false>
            <<<dim3(8, 32, 1), blk, 0, stream>>>(
            batts, D, 0, 0, wsp + (size_t)3 * D * D, D, 0, 0, b + 3 * D, 0,
            outbuf, D, 0, 0, BS, D, D, 1, 1.0f);
    };

    auto ffn = [&](const unsigned* xs, const WT* w1, const WT* b1,
                   const WT* w2, const WT* b2) {
        wsplit_kernel<<<dim3(FF / 64, D / 64, 1), blk, 0, stream>>>(w1, wsp, D, FF);
        mm_kernel<128, 128, A_SPLIT, B_SPLIT, true, true>
            <<<dim3(FF / 128, BS / 128, 1), blk, 0, stream>>>(
            xs, D, 0, 0, wsp, D, 0, 0, b1, 0,
            hidden, FF, 0, 0, BS, FF, D, 1, 1.0f);
        wsplit_kernel<<<dim3(D / 64, FF / 64, 1), blk, 0, stream>>>(w2, wsp, FF, D);
        mm_kernel<128, 64, A_SPLIT, B_SPLIT, false, false>
            <<<dim3(8, 32, 1), blk, 0, stream>>>(
            hidden, FF, 0, 0, wsp, FF, 0, 0, b2, 0,
            bmha, D, 0, 0, BS, D, FF, 1, 1.0f);
    };

    // ---------------- encoder ----------------
    embed_kernel<<<dim3(BS), blk, 0, stream>>>(src, src_emb, bx, bxs);
    for (int l = 0; l < NLAYERS; ++l) {
        attn(bxs, bxs, enc_qkvo_w + (size_t)l * 4 * D * D,
             enc_qkvo_b + (size_t)l * 4 * D, src, 0, bmha);
        ln_kernel<<<dim3(BS), blk, 0, stream>>>(bx, bmha,
            enc_ln_g + (size_t)l * 2 * D, enc_ln_b + (size_t)l * 2 * D, bxs);
        ffn(bxs, enc_ff1_w + (size_t)l * D * FF, enc_ff1_b + (size_t)l * FF,
            enc_ff2_w + (size_t)l * FF * D, enc_ff2_b + (size_t)l * D);
        ln_kernel<<<dim3(BS), blk, 0, stream>>>(bx, bmha,
            enc_ln_g + (size_t)l * 2 * D + D, enc_ln_b + (size_t)l * 2 * D + D, bxs);
    }

    // ---------------- decoder ----------------
    embed_kernel<<<dim3(BS), blk, 0, stream>>>(tgt, tgt_emb, by, bys);
    for (int l = 0; l < NLAYERS; ++l) {
        attn(bys, bys, dec_sa_w + (size_t)l * 4 * D * D,
             dec_sa_b + (size_t)l * 4 * D, nullptr, 1, bmha);
        ln_kernel<<<dim3(BS), blk, 0, stream>>>(by, bmha,
            dec_ln_g + (size_t)l * 3 * D, dec_ln_b + (size_t)l * 3 * D, bys);
        // cross-attention; reference masks keys with TGT padding (bug-for-bug)
        attn(bys, bxs, dec_ca_w + (size_t)l * 4 * D * D,
             dec_ca_b + (size_t)l * 4 * D, tgt, 0, bmha);
        ln_kernel<<<dim3(BS), blk, 0, stream>>>(by, bmha,
            dec_ln_g + (size_t)l * 3 * D + D, dec_ln_b + (size_t)l * 3 * D + D, bys);
        ffn(bys, dec_ff1_w + (size_t)l * D * FF, dec_ff1_b + (size_t)l * FF,
            dec_ff2_w + (size_t)l * FF * D, dec_ff2_b + (size_t)l * D);
        ln_kernel<<<dim3(BS), blk, 0, stream>>>(by, bmha,
            dec_ln_g + (size_t)l * 3 * D + 2 * D, dec_ln_b + (size_t)l * 3 * D + 2 * D,
            bys);
    }

    // ---------------- final projection to vocab ----------------
    wsplit_kernel<<<dim3((V + 63) / 64, D / 64, 1), blk, 0, stream>>>(out_w, vws, D, V);
    mm_kernel<128, 128, A_SPLIT, B_SPLIT, false, false>
        <<<dim3((V + 127) / 128, BS / 128, 1), blk, 0, stream>>>(
        bys, D, 0, 0, vws, D, 0, 0, out_b, 0,
        out, V, 0, 0, BS, V, D, 1, 1.0f);
}